// Round 5
// baseline (4983.334 us; speedup 1.0000x reference)
//
// Encoder-decoder LSTM + dot attention + linear, MI355X fp32.  R9
// R5-R8 post-mortem: the L2-local exchange lever is falsified 3 ways (no
// co-XCD pair found under rr or chunked mapping; probes fail; forced fast
// path hangs/spins). All fast-path machinery removed; agent-atomic exchange
// (proven, R4 = 1622us/scan) restored.
// R9 lever: wave-local gate reduction. New lane map (lane = g*16+s*4+dlow,
// wave = dhigh) puts the 4 k-quarter partials AND the 4 gates of each dim in
// one wave: reduce = shfl_xor 4,8 (same tree as R4 -> bit-identical), gate
// gather = shfl_xor 16,32 + selects, c/h replicated in-register. Deletes
// act_s LDS round trip + barrier #1 (~400-600cy/step) and issues the publish
// store ~300cy earlier. One barrier/step. Roles: g0/g1 publish even/odd dim,
// g2 ds_writes h_rep, g3 writes states (s==0 lanes only; s=1..3 redundant).
// Pred: scans 1622 -> 1350-1480us, FETCH ~100MB, WRITE ~192MB, total ~3450us.
#include <hip/hip_runtime.h>
#include <math.h>

#define HD 256
#define GD 1024   // 4*H
#define TT 1024
#define BB 64
#define NT 512    // scan block size

__device__ __forceinline__ float sig_(float x)  { return 1.f / (1.f + __expf(-x)); }
__device__ __forceinline__ float tanh_(float x) { return 1.f - 2.f / (1.f + __expf(2.f * x)); }

// ---------------- prep: transpose Whh -> [k][j], bias sums, zero exchange ----------------
__global__ __launch_bounds__(256) void prep_kernel(
    const float* __restrict__ eW, const float* __restrict__ eb1, const float* __restrict__ eb2,
    const float* __restrict__ dW, const float* __restrict__ db1, const float* __restrict__ db2,
    float* __restrict__ WTe, float* __restrict__ WTd,
    float* __restrict__ be, float* __restrict__ bd,
    unsigned long long* __restrict__ ex)   // [B][2][256] tagged slots
{
    int idx = blockIdx.x * 256 + threadIdx.x;
    if (idx < GD * HD) {
        int j = idx / HD, k = idx % HD;      // Whh[j][k]
        WTe[k * GD + j] = eW[idx];
        WTd[k * GD + j] = dW[idx];
    }
    if (idx < GD) {
        be[idx] = eb1[idx] + eb2[idx];
        bd[idx] = db1[idx] + db2[idx];
    }
    if (idx < BB * 2 * 256) ex[idx] = 0ULL;   // tags=0 (< any expected tag)
}

// ---------------- LSTM scan: 4 blocks/chain, weights in VGPRs, tagged exchange ----------
// block = (b = blk&63, q = blk>>6); q owns hidden dims [64q, 64q+64)
// lane map: g = lane>>4 (gate), s = (lane>>2)&3 (k-quarter), dl = lane&3
//           d = wave*4 + dl (dim-pair), rows jg0 = g*256 + q*64 + 2d (+1)
__global__ __launch_bounds__(NT, 2) void lstm_scan(
    const float* __restrict__ x,       // [B,T]
    const float* __restrict__ Wih,     // [4H]
    const float* __restrict__ bias,    // [4H] (bih+bhh)
    const float* __restrict__ WT,      // [H][4H]
    const float* __restrict__ h_init,  // nullptr, or enc_states (reads [b][T-1][:])
    float* __restrict__ states,        // [B,T,H]
    unsigned long long* __restrict__ ex,  // [B][2][256] tagged slots (agent scope)
    unsigned tag0)                     // 0 for encoder, 1024 for decoder
{
    const int b    = (int)blockIdx.x & 63;
    const int q    = (int)blockIdx.x >> 6;
    const int tid  = threadIdx.x;
    const int lane = tid & 63;
    const int wv   = tid >> 6;          // 0..7
    const int g    = lane >> 4;         // 0:i 1:f 2:g 3:o
    const int s    = (lane >> 2) & 3;   // k-quarter
    const int dl   = lane & 3;
    const int d    = wv * 4 + dl;       // dim-pair 0..31 (dims 2d, 2d+1)
    const int jg0  = g * 256 + q * 64 + 2 * d;  // global gate row

    __shared__ float h_rep[4][264];
    __shared__ float x_s[TT];

    // ---- weights for rows jg0, jg0+1 over k in [64s,64s+64): 128 VGPRs ----
    float4 w0[16], w1[16];
    {
        const float* basek = WT + (size_t)(s * 64) * GD;
        #pragma unroll
        for (int i = 0; i < 16; ++i) {
            const float* p0 = basek + (size_t)(4 * i) * GD + jg0;
            w0[i] = make_float4(p0[0], p0[GD], p0[2 * GD], p0[3 * GD]);
            const float* p1 = p0 + 1;
            w1[i] = make_float4(p1[0], p1[GD], p1[2 * GD], p1[3 * GD]);
        }
    }
    const float wih0 = Wih[jg0], wih1 = Wih[jg0 + 1];
    const float bj0  = bias[jg0], bj1  = bias[jg0 + 1];

    for (int i = tid; i < TT; i += NT) x_s[i] = x[b * TT + i];
    if (tid < 256) {
        float hv = h_init ? h_init[((size_t)b * TT + (TT - 1)) * HD + tid] : 0.f;
        h_rep[tid >> 6][tid & 63] = hv;
    }
    float c0 = 0.f, c1 = 0.f;   // cell state for dims 2d, 2d+1 (x4 replicated over g)
    __syncthreads();

    for (int t = 0; t < TT; ++t) {
        // ---- gate pre-activation partial over this thread's k-quarter ----
        const float xt = x_s[t];
        float a0p, a1p, a0q = 0.f, a1q = 0.f;
        if (s == 0) { a0p = fmaf(xt, wih0, bj0); a1p = fmaf(xt, wih1, bj1); }
        else        { a0p = 0.f;                 a1p = 0.f; }
        const float4* h4 = (const float4*)(&h_rep[s][0]);
        #pragma unroll
        for (int i = 0; i < 8; ++i) {
            float4 hv = h4[i];
            a0p = fmaf(hv.x, w0[i].x, a0p); a0p = fmaf(hv.y, w0[i].y, a0p);
            a0p = fmaf(hv.z, w0[i].z, a0p); a0p = fmaf(hv.w, w0[i].w, a0p);
            a1p = fmaf(hv.x, w1[i].x, a1p); a1p = fmaf(hv.y, w1[i].y, a1p);
            a1p = fmaf(hv.z, w1[i].z, a1p); a1p = fmaf(hv.w, w1[i].w, a1p);
        }
        #pragma unroll
        for (int i = 8; i < 16; ++i) {
            float4 hv = h4[i];
            a0q = fmaf(hv.x, w0[i].x, a0q); a0q = fmaf(hv.y, w0[i].y, a0q);
            a0q = fmaf(hv.z, w0[i].z, a0q); a0q = fmaf(hv.w, w0[i].w, a0q);
            a1q = fmaf(hv.x, w1[i].x, a1q); a1q = fmaf(hv.y, w1[i].y, a1q);
            a1q = fmaf(hv.z, w1[i].z, a1q); a1q = fmaf(hv.w, w1[i].w, a1q);
        }
        float a0 = a0p + a0q;
        float a1 = a1p + a1q;
        // reduce over k-quarters (lanes differing in bits 2-3): same tree as R4
        a0 += __shfl_xor(a0, 4); a0 += __shfl_xor(a0, 8);
        a1 += __shfl_xor(a1, 4); a1 += __shfl_xor(a1, 8);
        // activation by own gate
        float av0 = (g == 2) ? tanh_(a0) : sig_(a0);
        float av1 = (g == 2) ? tanh_(a1) : sig_(a1);
        // gather the other 3 gates (lanes differing in bits 4-5)
        float p16_0 = __shfl_xor(av0, 16), p32_0 = __shfl_xor(av0, 32);
        float p48_0 = __shfl_xor(p32_0, 16);
        float p16_1 = __shfl_xor(av1, 16), p32_1 = __shfl_xor(av1, 32);
        float p48_1 = __shfl_xor(p32_1, 16);
        float gi0, gf0, gg0, go0, gi1, gf1, gg1, go1;
        if      (g == 0) { gi0=av0;   gf0=p16_0; gg0=p32_0; go0=p48_0;
                           gi1=av1;   gf1=p16_1; gg1=p32_1; go1=p48_1; }
        else if (g == 1) { gi0=p16_0; gf0=av0;   gg0=p48_0; go0=p32_0;
                           gi1=p16_1; gf1=av1;   gg1=p48_1; go1=p32_1; }
        else if (g == 2) { gi0=p32_0; gf0=p48_0; gg0=av0;   go0=p16_0;
                           gi1=p32_1; gf1=p48_1; gg1=av1;   go1=p16_1; }
        else             { gi0=p48_0; gf0=p32_0; gg0=p16_0; go0=av0;
                           gi1=p48_1; gf1=p32_1; gg1=p16_1; go1=av1; }
        // cell + hidden (replicated x4 over g-lanes: identical arithmetic)
        c0 = fmaf(gf0, c0, gi0 * gg0);
        c1 = fmaf(gf1, c1, gi1 * gg1);
        const float h0 = go0 * tanh_(c0);
        const float h1 = go1 * tanh_(c1);

        const unsigned tag = tag0 + (unsigned)t + 1u;
        unsigned long long* ssl = ex + ((size_t)b * 2 + (t & 1)) * 256;
        // role-split side effects (s==0 lanes only; publish issues FIRST)
        if (s == 0) {
            if (g < 2) {
                unsigned long long pk = ((unsigned long long)tag << 32)
                    | (unsigned long long)__float_as_uint(g == 0 ? h0 : h1);
                __hip_atomic_store(&ssl[q * 64 + 2 * d + g], pk,
                                   __ATOMIC_RELAXED, __HIP_MEMORY_SCOPE_AGENT);
            } else if (g == 2) {
                *(float2*)(&h_rep[q][2 * d]) = make_float2(h0, h1);
            } else {
                *(float2*)(&states[((size_t)(b * TT + t)) * HD + q * 64 + 2 * d])
                    = make_float2(h0, h1);
            }
        }
        // poll remote quarters (threads 0..255 map 1:1 to slots)
        if (tid < 256) {
            const int dq = tid >> 6, dk = tid & 63;   // wave-uniform dq
            if (dq != q) {
                unsigned long long u;
                do {
                    u = __hip_atomic_load(&ssl[tid], __ATOMIC_RELAXED, __HIP_MEMORY_SCOPE_AGENT);
                } while ((unsigned)(u >> 32) != tag);
                h_rep[dq][dk] = __uint_as_float((unsigned)u);
            }
        }
        __syncthreads();   // h replicas ready for t+1
    }
}

// ---------------- proj: ew[b][t]=E·w1, hw[b][t]=Hx·w2 (one wave per row) ----------------
__global__ __launch_bounds__(256) void proj_kernel(
    const float* __restrict__ enc_states, const float* __restrict__ dec_hs,
    const float* __restrict__ linW, float* __restrict__ ew, float* __restrict__ hw)
{
    const int lane = threadIdx.x & 63;
    const int wid  = blockIdx.x * 4 + (threadIdx.x >> 6);
    const int nw   = gridDim.x * 4;
    const float4 w1 = ((const float4*)linW)[lane];
    const float4 w2 = ((const float4*)(linW + HD))[lane];
    for (int o = wid; o < BB * TT; o += nw) {
        float4 v1 = ((const float4*)(enc_states + (size_t)o * HD))[lane];
        float4 v2 = ((const float4*)(dec_hs     + (size_t)o * HD))[lane];
        float s1 = v1.x * w1.x + v1.y * w1.y + v1.z * w1.z + v1.w * w1.w;
        float s2 = v2.x * w2.x + v2.y * w2.y + v2.z * w2.z + v2.w * w2.w;
        #pragma unroll
        for (int m = 1; m < 64; m <<= 1) {
            s1 += __shfl_xor(s1, m);
            s2 += __shfl_xor(s2, m);
        }
        if (lane == 0) { ew[o] = s1; hw[o] = s2; }
    }
}

// ---------------- attention v2: 32 td rows/block, 4x8 register tile ----------------
// Hx[k][td] stride 36 (16B-aligned rows): per k one wave-uniform ds_read_b128
// E[k][te]: lane-consecutive b32 reads (conflict-free, broadcast across td groups)
#define TD2  32    // td rows per block
#define TEC2 256   // te chunk
#define KC2  32    // k chunk
__global__ __launch_bounds__(256) void attn_kernel(
    const float* __restrict__ enc_states,  // [B][T][H]
    const float* __restrict__ dec_hs,      // [B][T][H]
    const float* __restrict__ ew, const float* __restrict__ hw,
    const float* __restrict__ lin_b,
    float* __restrict__ out)               // [B][T]
{
    const int b   = blockIdx.y;
    const int td0 = blockIdx.x * TD2;
    const int tid = threadIdx.x;
    const int tdt = tid >> 5;   // 0..7 (4 td rows each)
    const int tet = tid & 31;   // 0..31

    __shared__ float Hx[HD][TD2 + 4];   // stride 36: rows 16B-aligned
    __shared__ float E[KC2][TEC2];

    // stage Hx: thread -> (td = tid>>3, 32-k chunk = (tid&7)*32)
    {
        const int td = tid >> 3;
        const int kc = (tid & 7) * 32;
        const float* src = dec_hs + ((size_t)b * TT + td0 + td) * HD + kc;
        #pragma unroll
        for (int qq = 0; qq < 8; ++qq) {
            float4 v = ((const float4*)(src + qq * 4))[0];
            Hx[kc + qq * 4 + 0][td] = v.x;
            Hx[kc + qq * 4 + 1][td] = v.y;
            Hx[kc + qq * 4 + 2][td] = v.z;
            Hx[kc + qq * 4 + 3][td] = v.w;
        }
    }

    float M[4]  = {-1e30f, -1e30f, -1e30f, -1e30f};
    float Nm[4] = {0.f, 0.f, 0.f, 0.f};
    float Dn[4] = {0.f, 0.f, 0.f, 0.f};

    for (int tc = 0; tc < TT / TEC2; ++tc) {
        const int te0 = tc * TEC2;
        float S[4][8] = {{0.f}};
        for (int kc = 0; kc < HD / KC2; ++kc) {
            const int k0 = kc * KC2;
            __syncthreads();
            {   // stage E chunk: thread = te row, 32 consecutive k
                const float* src = enc_states + ((size_t)b * TT + te0 + tid) * HD + k0;
                #pragma unroll
                for (int qq = 0; qq < 8; ++qq) {
                    float4 v = ((const float4*)(src + qq * 4))[0];
                    E[qq * 4 + 0][tid] = v.x;
                    E[qq * 4 + 1][tid] = v.y;
                    E[qq * 4 + 2][tid] = v.z;
                    E[qq * 4 + 3][tid] = v.w;
                }
            }
            __syncthreads();
            #pragma unroll 4
            for (int k = 0; k < KC2; ++k) {
                const float4 hx4 = *(const float4*)(&Hx[k0 + k][tdt * 4]);
                #pragma unroll
                for (int i = 0; i < 8; ++i) {
                    const float e = E[k][tet + 32 * i];
                    S[0][i] = fmaf(hx4.x, e, S[0][i]);
                    S[1][i] = fmaf(hx4.y, e, S[1][i]);
                    S[2][i] = fmaf(hx4.z, e, S[2][i]);
                    S[3][i] = fmaf(hx4.w, e, S[3][i]);
                }
            }
        }
        float ewv[8];
        #pragma unroll
        for (int i = 0; i < 8; ++i) ewv[i] = ew[(size_t)b * TT + te0 + tet + 32 * i];
        #pragma unroll
        for (int r = 0; r < 4; ++r) {
            float cm = S[r][0];
            #pragma unroll
            for (int i = 1; i < 8; ++i) cm = fmaxf(cm, S[r][i]);
            #pragma unroll
            for (int m = 1; m < 32; m <<= 1) cm = fmaxf(cm, __shfl_xor(cm, m));
            const float newM  = fmaxf(M[r], cm);
            const float scale = __expf(M[r] - newM);
            float nl = 0.f, dl = 0.f;
            #pragma unroll
            for (int i = 0; i < 8; ++i) {
                const float p = __expf(S[r][i] - newM);
                dl += p;
                nl = fmaf(p, ewv[i], nl);
            }
            #pragma unroll
            for (int m = 1; m < 32; m <<= 1) {
                nl += __shfl_xor(nl, m);
                dl += __shfl_xor(dl, m);
            }
            Nm[r] = Nm[r] * scale + nl;
            Dn[r] = Dn[r] * scale + dl;
            M[r]  = newM;
        }
    }

    if (tet == 0) {
        const float lb = lin_b[0];
        #pragma unroll
        for (int r = 0; r < 4; ++r) {
            const int td = td0 + tdt * 4 + r;
            out[(size_t)b * TT + td] = Nm[r] / Dn[r] + hw[(size_t)b * TT + td] + lb;
        }
    }
}

extern "C" void kernel_launch(void* const* d_in, const int* in_sizes, int n_in,
                              void* d_out, int out_size, void* d_ws, size_t ws_size,
                              hipStream_t stream)
{
    const float* x    = (const float*)d_in[0];
    const float* eWih = (const float*)d_in[1];
    const float* eWhh = (const float*)d_in[2];
    const float* ebih = (const float*)d_in[3];
    const float* ebhh = (const float*)d_in[4];
    const float* dWih = (const float*)d_in[5];
    const float* dWhh = (const float*)d_in[6];
    const float* dbih = (const float*)d_in[7];
    const float* dbhh = (const float*)d_in[8];
    const float* linW = (const float*)d_in[9];
    const float* linb = (const float*)d_in[10];
    float* out = (float*)d_out;

    float* p = (float*)d_ws;
    float* WTe = p;        p += (size_t)GD * HD;
    float* WTd = p;        p += (size_t)GD * HD;
    float* be  = p;        p += GD;
    float* bd  = p;        p += GD;
    float* enc_states = p; p += (size_t)BB * TT * HD;
    float* dec_hs = p;     p += (size_t)BB * TT * HD;
    float* ew = p;         p += (size_t)BB * TT;
    float* hw = p;         p += (size_t)BB * TT;
    unsigned long long* ex = (unsigned long long*)p; p += (size_t)BB * 2 * 256 * 2;

    prep_kernel<<<(GD * HD + 255) / 256, 256, 0, stream>>>(
        eWhh, ebih, ebhh, dWhh, dbih, dbhh, WTe, WTd, be, bd, ex);

    // plain launches: 256 blocks on 256 CUs -> co-resident by capacity (R8-proven)
    lstm_scan<<<256, NT, 0, stream>>>(
        x, eWih, be, WTe, nullptr, enc_states, ex, 0u);
    lstm_scan<<<256, NT, 0, stream>>>(
        x, dWih, bd, WTd, enc_states, dec_hs, ex, 1024u);

    proj_kernel<<<256, 256, 0, stream>>>(enc_states, dec_hs, linW, ew, hw);
    attn_kernel<<<dim3(TT / TD2, BB), 256, 0, stream>>>(enc_states, dec_hs, ew, hw, linb, out);
}